// Round 7
// baseline (449.248 us; speedup 1.0000x reference)
//
#include <hip/hip_runtime.h>

#define NE 8          // routed experts
#define HD 1024       // hidden
#define MD 2048       // intermediate
#define NT 2048       // tokens (2*1024)
#define NSH 4224      // shared-expert row base (>= padded routed rows, %16==0)

typedef __attribute__((ext_vector_type(8))) short s16x8;
typedef __attribute__((ext_vector_type(4))) float f32x4;
typedef __attribute__((ext_vector_type(8))) unsigned short u16x8;
typedef __attribute__((ext_vector_type(4))) unsigned short u16x4;

__device__ __forceinline__ unsigned short f2bf(float f) {
    union { float f; unsigned int i; } v; v.f = f;
    unsigned int u = v.i;
    return (unsigned short)((u + 0x7FFFu + ((u >> 16) & 1u)) >> 16);
}
__device__ __forceinline__ float bf2f(unsigned short u) {
    union { unsigned int i; float f; } v; v.i = ((unsigned int)u) << 16; return v.f;
}
// native packed f32->bf16 (RNE, matches f2bf); src0 -> low 16 bits
__device__ __forceinline__ unsigned int cvtpk(float lo, float hi) {
    unsigned int r;
    asm volatile("v_cvt_pk_bf16_f32 %0, %1, %2" : "=v"(r) : "v"(lo), "v"(hi));
    return r;
}

// async 16B global -> LDS (HW adds lane*16 to wave-uniform LDS base)
__device__ __forceinline__ void gld16(const unsigned short* g, short* l) {
    __builtin_amdgcn_global_load_lds(
        (const __attribute__((address_space(1))) unsigned int*)g,
        (__attribute__((address_space(3))) unsigned int*)l,
        16, 0, 0);
}

// padded prefix base for expert e (replaces k_scan; cnt loads are L2 broadcast)
__device__ __forceinline__ int padbase(const int* __restrict__ cnt, int e) {
    int run = 0;
    for (int ee = 0; ee < e; ee++) run += (cnt[ee] + 15) & ~15;
    return run;
}

// Blocked bf16 layout for B-operands and h:
//   elem(r, k) at ((r>>4)*(K>>3) + (k>>3))*128 + (r&15)*8 + (k&7)
// A 16-row x 32-k slab is 1KB contiguous = one wave's global_load_lds.

// ---------------- K0: all weights fp32 -> blocked bf16, LDS-free ----------
// Thread owns one OUTPUT column ni; 8 row-strided lane-coalesced dword loads
// per k-chunk (256B/instr), 4 cvt_pk, one 16B store contiguous across lanes.
// grid.x: [0,128) = gate+up interleaved (16 ni-blk x 8 kc-blk),
//         [128,192) = down (4 ni-blk x 16 kc-blk).  grid.y = expert (9).
__global__ __launch_bounds__(256) void k_cvt_w(
    const float* __restrict__ wg, const float* __restrict__ wu,
    const float* __restrict__ swg, const float* __restrict__ swu,
    const float* __restrict__ wd, const float* __restrict__ swd,
    unsigned short* __restrict__ ogu, unsigned short* __restrict__ od)
{
    int b = blockIdx.x, e = blockIdx.y;
    int tid = threadIdx.x;
    if (b < 128) {
        int nb = b & 15, kb = b >> 4;            // 16 ni-blocks, 8 kc-blocks
        int ni = nb * 256 + tid;                 // interleaved col 0..4095
        const float* sg = (e < NE) ? wg + (size_t)e * HD * MD : swg;
        const float* su = (e < NE) ? wu + (size_t)e * HD * MD : swu;
        const float* s = (ni & 1) ? su : sg;
        int n = ni >> 1;                         // source col 0..2047
        unsigned short* dst = ogu + (size_t)e * (2 * MD) * HD
                            + (size_t)(ni >> 4) * 128 * 128 + (ni & 15) * 8;
        for (int kc = kb * 16; kc < kb * 16 + 16; kc++) {
            float v[8];
            #pragma unroll
            for (int j = 0; j < 8; j++) v[j] = s[(size_t)(kc * 8 + j) * MD + n];
            uint4 r;
            r.x = cvtpk(v[0], v[1]); r.y = cvtpk(v[2], v[3]);
            r.z = cvtpk(v[4], v[5]); r.w = cvtpk(v[6], v[7]);
            *(uint4*)(dst + (size_t)kc * 128) = r;
        }
    } else {
        int b2 = b - 128;
        int nb = b2 & 3, kb = b2 >> 2;           // 4 ni-blocks, 16 kc-blocks
        int ni = nb * 256 + tid;                 // col 0..1023
        const float* s = (e < NE) ? wd + (size_t)e * MD * HD : swd;
        unsigned short* dst = od + (size_t)e * MD * HD
                            + (size_t)(ni >> 4) * 256 * 128 + (ni & 15) * 8;
        for (int kc = kb * 16; kc < kb * 16 + 16; kc++) {
            float v[8];
            #pragma unroll
            for (int j = 0; j < 8; j++) v[j] = s[(size_t)(kc * 8 + j) * HD + ni];
            uint4 r;
            r.x = cvtpk(v[0], v[1]); r.y = cvtpk(v[2], v[3]);
            r.z = cvtpk(v[4], v[5]); r.w = cvtpk(v[6], v[7]);
            *(uint4*)(dst + (size_t)kc * 128) = r;
        }
    }
}

// ---------------- K1: routing + x bf16 convert (one wave per token) -------
__global__ __launch_bounds__(256) void k_route(
    const float* __restrict__ x, const float* __restrict__ gw,
    const float* __restrict__ beta,
    int* __restrict__ cnt, int* __restrict__ list, int* __restrict__ slot,
    float* __restrict__ rprob, unsigned short* __restrict__ xb)
{
    int wave = threadIdx.x >> 6, lane = threadIdx.x & 63;
    int t = blockIdx.x * 4 + wave;
    const float4* xp = (const float4*)(x + (size_t)t * HD) + lane * 4;
    float4 xv[4];
    #pragma unroll
    for (int j = 0; j < 4; j++) xv[j] = xp[j];

    u16x8 o0, o1;
    o0[0] = f2bf(xv[0].x); o0[1] = f2bf(xv[0].y); o0[2] = f2bf(xv[0].z); o0[3] = f2bf(xv[0].w);
    o0[4] = f2bf(xv[1].x); o0[5] = f2bf(xv[1].y); o0[6] = f2bf(xv[1].z); o0[7] = f2bf(xv[1].w);
    o1[0] = f2bf(xv[2].x); o1[1] = f2bf(xv[2].y); o1[2] = f2bf(xv[2].z); o1[3] = f2bf(xv[2].w);
    o1[4] = f2bf(xv[3].x); o1[5] = f2bf(xv[3].y); o1[6] = f2bf(xv[3].z); o1[7] = f2bf(xv[3].w);
    *(u16x8*)(xb + (size_t)t * HD + lane * 16) = o0;
    *(u16x8*)(xb + (size_t)t * HD + lane * 16 + 8) = o1;

    float logit[NE];
    #pragma unroll
    for (int e = 0; e < NE; e++) {
        const float4* gp = (const float4*)(gw + e * HD) + lane * 4;
        float s = 0.f;
        #pragma unroll
        for (int j = 0; j < 4; j++) {
            float4 g = gp[j];
            s += xv[j].x * g.x + xv[j].y * g.y + xv[j].z * g.z + xv[j].w * g.w;
        }
        for (int off = 32; off > 0; off >>= 1) s += __shfl_xor(s, off);
        logit[e] = s;
    }
    if (lane == 0) {
        float v[NE];
        #pragma unroll
        for (int e = 0; e < NE; e++) v[e] = logit[e] + beta[e];
        int i1 = 0; float m1 = v[0];
        #pragma unroll
        for (int e = 1; e < NE; e++) if (v[e] > m1) { m1 = v[e]; i1 = e; }
        int i2 = -1; float m2 = -3.4e38f;
        #pragma unroll
        for (int e = 0; e < NE; e++) if (e != i1 && v[e] > m2) { m2 = v[e]; i2 = e; }
        if (i2 < 0) i2 = (i1 + 1) & 7;
        float p1 = 1.f / (1.f + __expf(-logit[i1]));
        float p2 = 1.f / (1.f + __expf(-logit[i2]));
        int pos1 = atomicAdd(cnt + i1, 1);
        list[i1 * NT + pos1] = t; slot[t * 2 + 0] = (i1 << 16) | pos1; rprob[t * 2 + 0] = p1;
        int pos2 = atomicAdd(cnt + i2, 1);
        list[i2 * NT + pos2] = t; slot[t * 2 + 1] = (i2 << 16) | pos2; rprob[t * 2 + 1] = p2;
    }
}

// ---------------- K3: gathered gate+up GEMM (R6-verified config) ----------
// 3D sparse grid + tok LDS + 4 blk/CU + direct scattered h stores
// (verified counters: 86us, FETCH 75MB, WRITE 24.6MB, 0 conflicts).
__global__ __launch_bounds__(256, 4) void k_gateup(
    const unsigned short* __restrict__ x,
    const unsigned short* __restrict__ wgu,
    const int* __restrict__ cnt, const int* __restrict__ list,
    unsigned short* __restrict__ h)
{
    int e = blockIdx.z;
    int i0 = blockIdx.y * 128;
    int n0 = blockIdx.x * 128;              // interleaved col space [0, 2*MD)
    int cnte = (e < NE) ? cnt[e] : NT;
    if (i0 >= cnte) return;
    int rbase = (e < NE) ? padbase(cnt, e) : NSH;
    const unsigned short* wb = wgu + (size_t)e * (2 * MD) * HD;

    __shared__ short As[2][128 * 32];
    __shared__ short Bs[2][8 * 512];        // 8 slabs of [4 chunk][16 ni][8 k]
    __shared__ int tok[128];

    int tid = threadIdx.x;
    int lane = tid & 63, wave = tid >> 6;
    if (tid < 128) {
        int gi = i0 + tid;
        tok[tid] = (e < NE) ? ((gi < cnte) ? list[e * NT + gi] : list[e * NT]) : gi;
    }
    __syncthreads();

    int rr = wave * 32 + (lane >> 2);
    int kc = ((lane & 3) ^ ((lane >> 3) & 3)) * 8;   // A source chunk swizzle
    size_t gaA0 = (size_t)tok[rr] * HD + kc;
    size_t gaA1 = (size_t)tok[rr + 16] * HD + kc;
    const int KC = HD / 8;   // 128
    size_t gaB0 = ((size_t)((n0 >> 4) + 2 * wave) * KC) * 128 + lane * 8;
    size_t gaB1 = gaB0 + (size_t)KC * 128;
    int loA0 = (wave * 32) * 32, loA1 = (wave * 32 + 16) * 32;
    int loB0 = (2 * wave) * 512, loB1 = (2 * wave + 1) * 512;

    int wr = (wave >> 1) * 64, wc = (wave & 1) * 64;
    int m = lane & 15, q = lane >> 4;
    int sa = (m >> 1) & 3;                  // A read-side swizzle (yields true chunk q)

    f32x4 acc[4][4];
    #pragma unroll
    for (int a = 0; a < 4; a++)
        #pragma unroll
        for (int b = 0; b < 4; b++) acc[a][b] = (f32x4)0.f;

    gld16(x + gaA0, &As[0][loA0]);
    gld16(x + gaA1, &As[0][loA1]);
    gld16(wb + gaB0, &Bs[0][loB0]);
    gld16(wb + gaB1, &Bs[0][loB1]);

    int it = 0;
    for (int k0 = 0; k0 < HD; k0 += 32, it ^= 1) {
        __syncthreads();   // drains this buf's prefetch (issued one iter ago)
        int nk = k0 + 32;
        if (nk < HD) {
            int nb = it ^ 1;
            gld16(x + gaA0 + nk, &As[nb][loA0]);
            gld16(x + gaA1 + nk, &As[nb][loA1]);
            gld16(wb + gaB0 + (size_t)nk * 16, &Bs[nb][loB0]);
            gld16(wb + gaB1 + (size_t)nk * 16, &Bs[nb][loB1]);
        }
        s16x8 af[4];
        #pragma unroll
        for (int ti2 = 0; ti2 < 4; ti2++)
            af[ti2] = *(const s16x8*)(&As[it][(wr + ti2 * 16 + m) * 32 + (q ^ sa) * 8]);
        #pragma unroll
        for (int tj = 0; tj < 4; tj++) {
            s16x8 bf = *(const s16x8*)(&Bs[it][((wave & 1) * 4 + tj) * 512 + q * 128 + m * 8]);
            #pragma unroll
            for (int ti2 = 0; ti2 < 4; ti2++)
                acc[ti2][tj] = __builtin_amdgcn_mfma_f32_16x16x32_bf16(af[ti2], bf, acc[ti2][tj], 0, 0, 0);
        }
    }
    // epilogue: pair gate/up across adjacent lanes; even lanes write silu(g)*u
    #pragma unroll
    for (int ti2 = 0; ti2 < 4; ti2++)
        #pragma unroll
        for (int tj = 0; tj < 4; tj++)
            #pragma unroll
            for (int r = 0; r < 4; r++) {
                float v = acc[ti2][tj][r];
                float uo = __shfl_xor(v, 1);
                int gi = i0 + wr + ti2 * 16 + q * 4 + r;
                if (!(m & 1) && gi < cnte) {
                    float g = v;
                    float hv = (g / (1.f + __expf(-g))) * uo;
                    int col = (n0 + wc + tj * 16 + m) >> 1;
                    int rw = rbase + gi;
                    size_t hi = ((size_t)(rw >> 4) * (MD >> 3) + (col >> 3)) * 128
                              + (rw & 15) * 8 + (col & 7);
                    h[hi] = f2bf(hv);
                }
            }
}

// ---------------- K4: down projection (R6-verified config) ----------------
__global__ __launch_bounds__(256, 4) void k_down(
    const unsigned short* __restrict__ wd_all,
    const int* __restrict__ cnt,
    const unsigned short* __restrict__ h, unsigned short* __restrict__ eo)
{
    int e = blockIdx.z;
    int i0 = blockIdx.y * 128;
    int n0 = blockIdx.x * 128;
    int cnte = (e < NE) ? cnt[e] : NT;
    if (i0 >= cnte) return;
    int rbase = (e < NE) ? padbase(cnt, e) : NSH;
    const unsigned short* wd = wd_all + (size_t)e * MD * HD;

    __shared__ short As[2][8 * 512];
    __shared__ short Bd[2][8 * 512];

    int tid = threadIdx.x;
    int lane = tid & 63, wave = tid >> 6;
    int r0 = rbase + i0;                    // 16-aligned (padded bases)
    const int KC = MD / 8;   // 256
    size_t gaA0 = ((size_t)((r0 >> 4) + 2 * wave) * KC) * 128 + lane * 8;
    size_t gaA1 = gaA0 + (size_t)KC * 128;
    size_t gaB0 = ((size_t)((n0 >> 4) + 2 * wave) * KC) * 128 + lane * 8;
    size_t gaB1 = gaB0 + (size_t)KC * 128;
    int lo0 = (2 * wave) * 512, lo1 = (2 * wave + 1) * 512;

    int wr = (wave >> 1) * 64, wc = (wave & 1) * 64;
    int m = lane & 15, q = lane >> 4;

    f32x4 acc[4][4];
    #pragma unroll
    for (int a = 0; a < 4; a++)
        #pragma unroll
        for (int b = 0; b < 4; b++) acc[a][b] = (f32x4)0.f;

    gld16(h + gaA0, &As[0][lo0]);
    gld16(h + gaA1, &As[0][lo1]);
    gld16(wd + gaB0, &Bd[0][lo0]);
    gld16(wd + gaB1, &Bd[0][lo1]);

    int it = 0;
    for (int k0 = 0; k0 < MD; k0 += 32, it ^= 1) {
        __syncthreads();
        int nk = k0 + 32;
        if (nk < MD) {
            int nb = it ^ 1;
            gld16(h + gaA0 + (size_t)nk * 16, &As[nb][lo0]);
            gld16(h + gaA1 + (size_t)nk * 16, &As[nb][lo1]);
            gld16(wd + gaB0 + (size_t)nk * 16, &Bd[nb][lo0]);
            gld16(wd + gaB1 + (size_t)nk * 16, &Bd[nb][lo1]);
        }
        s16x8 af[4];
        #pragma unroll
        for (int ti2 = 0; ti2 < 4; ti2++)
            af[ti2] = *(const s16x8*)(&As[it][((wave >> 1) * 4 + ti2) * 512 + q * 128 + m * 8]);
        #pragma unroll
        for (int tj = 0; tj < 4; tj++) {
            s16x8 bd = *(const s16x8*)(&Bd[it][((wave & 1) * 4 + tj) * 512 + q * 128 + m * 8]);
            #pragma unroll
            for (int ti2 = 0; ti2 < 4; ti2++)
                acc[ti2][tj] = __builtin_amdgcn_mfma_f32_16x16x32_bf16(af[ti2], bd, acc[ti2][tj], 0, 0, 0);
        }
    }
    #pragma unroll
    for (int ti2 = 0; ti2 < 4; ti2++)
        #pragma unroll
        for (int tj = 0; tj < 4; tj++)
            #pragma unroll
            for (int r = 0; r < 4; r++) {
                int gi = i0 + wr + ti2 * 16 + q * 4 + r;
                if (gi < cnte) {
                    int col = n0 + wc + tj * 16 + m;
                    eo[(size_t)(rbase + gi) * HD + col] = f2bf(acc[ti2][tj][r]);
                }
            }
}

// ---------------- K5: weighted combine -> fp32 out ----------------
__global__ __launch_bounds__(256) void k_combine(
    const unsigned short* __restrict__ eo, const int* __restrict__ slot,
    const float* __restrict__ rprob, const int* __restrict__ cnt,
    float* __restrict__ out)
{
    int t = blockIdx.x;
    int s0 = slot[t * 2], s1 = slot[t * 2 + 1];
    float p0 = rprob[t * 2], p1 = rprob[t * 2 + 1];
    int e0 = s0 >> 16, e1 = s1 >> 16;
    int run = 0, b0 = 0, b1 = 0;
    for (int ee = 0; ee < NE; ee++) {
        if (ee == e0) b0 = run;
        if (ee == e1) b1 = run;
        run += (cnt[ee] + 15) & ~15;
    }
    int r0 = b0 + (s0 & 0xFFFF);
    int r1 = b1 + (s1 & 0xFFFF);
    int rs = NSH + t;
    int c = threadIdx.x * 4;
    u16x4 a = *(const u16x4*)(eo + (size_t)r0 * HD + c);
    u16x4 b = *(const u16x4*)(eo + (size_t)r1 * HD + c);
    u16x4 s = *(const u16x4*)(eo + (size_t)rs * HD + c);
    float4 res;
    res.x = p0 * bf2f(a[0]) + p1 * bf2f(b[0]) + bf2f(s[0]);
    res.y = p0 * bf2f(a[1]) + p1 * bf2f(b[1]) + bf2f(s[1]);
    res.z = p0 * bf2f(a[2]) + p1 * bf2f(b[2]) + bf2f(s[2]);
    res.w = p0 * bf2f(a[3]) + p1 * bf2f(b[3]) + bf2f(s[3]);
    *(float4*)(out + (size_t)t * HD + c) = res;
}

extern "C" void kernel_launch(void* const* d_in, const int* in_sizes, int n_in,
                              void* d_out, int out_size, void* d_ws, size_t ws_size,
                              hipStream_t stream)
{
    const float* x    = (const float*)d_in[0];
    const float* gw   = (const float*)d_in[1];
    const float* beta = (const float*)d_in[2];
    const float* wg   = (const float*)d_in[3];
    const float* wu   = (const float*)d_in[4];
    const float* wd   = (const float*)d_in[5];
    const float* swg  = (const float*)d_in[6];
    const float* swu  = (const float*)d_in[7];
    const float* swd  = (const float*)d_in[8];
    float* out = (float*)d_out;

    char* ws = (char*)d_ws;
    const size_t MB = (size_t)1 << 20;
    int*   cnt   = (int*)(ws + 0);
    int*   list  = (int*)(ws + 1024);
    int*   slot  = (int*)(ws + 1024 + 65536);
    float* rprob = (float*)(ws + 1024 + 65536 + 16384);
    unsigned short* xb   = (unsigned short*)(ws + 1 * MB);    // [2048][1024]
    unsigned short* eo   = (unsigned short*)(ws + 6 * MB);    // [6272][1024]
    unsigned short* wgut = (unsigned short*)(ws + 20 * MB);   // [9] blocked interleaved [4096 x 1024]
    unsigned short* wdt  = (unsigned short*)(ws + 92 * MB);   // [9] blocked [1024 x 2048]
    unsigned short* h    = (unsigned short*)(ws + 128 * MB);  // [6272 x 2048] blocked

    hipMemsetAsync(ws, 0, 128, stream);

    dim3 gc(192, NE + 1);
    k_cvt_w<<<gc, 256, 0, stream>>>(wg, wu, swg, swu, wd, swd, wgut, wdt);

    k_route<<<NT / 4, 256, 0, stream>>>(x, gw, beta, cnt, list, slot, rprob, xb);

    dim3 g3(2 * MD / 128, NT / 128, NE + 1);
    k_gateup<<<g3, 256, 0, stream>>>(xb, wgut, cnt, list, h);

    dim3 g4(HD / 128, NT / 128, NE + 1);
    k_down<<<g4, 256, 0, stream>>>(wdt, cnt, h, eo);

    k_combine<<<NT, 256, 0, stream>>>(eo, slot, rprob, cnt, out);
}